// Round 9
// baseline (278.345 us; speedup 1.0000x reference)
//
#include <hip/hip_runtime.h>

#define NB 2
#define NH 16
#define SEQ 2048
#define DMODEL 1024
#define DHEAD 64
// 0.125 (1/sqrt(DH)) / ln(2): folded into Wq so softmax is a bare exp2
#define QSCALE 0.18033688f

typedef __attribute__((ext_vector_type(8))) short bf16x8;
typedef __attribute__((ext_vector_type(4))) short bf16x4;
typedef __attribute__((ext_vector_type(4))) float f32x4;
typedef __attribute__((ext_vector_type(16))) float f32x16;
typedef __attribute__((ext_vector_type(4))) int i32x4;

static __device__ __forceinline__ unsigned short f2bf(float f) {
    unsigned int u = __float_as_uint(f);
    u += 0x7fffu + ((u >> 16) & 1u);   // RNE
    return (unsigned short)(u >> 16);
}
static __device__ __forceinline__ unsigned int pk2(float lo, float hi) {
    return (unsigned int)f2bf(lo) | ((unsigned int)f2bf(hi) << 16);
}
static __device__ __forceinline__ void gld_lds16(const unsigned short* g, unsigned short* l) {
    __builtin_amdgcn_global_load_lds(
        (const __attribute__((address_space(1))) unsigned int*)g,
        (__attribute__((address_space(3))) unsigned int*)l, 16, 0, 0);
}

// =====================================================================
// Prep v10: mask pack + weight transposes ONLY (2048 blocks). The
// q/k/v f32->bf16 copy phase (6144 blocks, ~75 MB traffic) is gone —
// conversion is fused into proj's A-staging.
// =====================================================================
__global__ __launch_bounds__(256) void prep_kernel(
    const int* __restrict__ mask, unsigned long long* __restrict__ mpack,
    const float* __restrict__ Wq, const float* __restrict__ Wk, const float* __restrict__ Wv,
    unsigned short* __restrict__ Wqt, unsigned short* __restrict__ Wkt,
    unsigned short* __restrict__ Wvt,
    const float* __restrict__ Wo, unsigned short* __restrict__ Wot)
{
    __shared__ __align__(16) float Ls[64][65];
    const int bid = blockIdx.x, t = threadIdx.x;

    if (bid < 1024) {
        // ---- mask pack ----
        const int wave = bid * 4 + (t >> 6);
        const int lane = t & 63;
        const int* row = mask + (size_t)wave * SEQ;
        unsigned long long* orow = mpack + (size_t)wave * (SEQ / 64);
        for (int w = 0; w < SEQ / 64; ++w) {
            int m = row[w * 64 + lane];
            unsigned long long bits = __ballot(m != 0);
            if (lane == 0) orow[w] = bits;
        }
    } else {
        // ---- weight transposes ----
        const float* S; unsigned short* D; float scale; int R, tile_r, tile_c, ostride;
        if (bid < 1792) {
            const int local = bid - 1024, z = local >> 4, sel = z >> 4, h = z & 15;
            S = (sel == 0 ? Wq : sel == 1 ? Wk : Wv) + (size_t)h * DMODEL * DHEAD;
            D = (sel == 0 ? Wqt : sel == 1 ? Wkt : Wvt) + (size_t)h * DMODEL * DHEAD;
            scale = (sel == 0) ? QSCALE : 1.0f;
            tile_r = (local & 15) * 64; tile_c = 0; R = DHEAD; ostride = DMODEL;
        } else {
            const int local = bid - 1792;
            S = Wo; D = Wot; scale = 1.0f;
            tile_c = (local & 15) * 64; tile_r = (local >> 4) * 64; R = DMODEL; ostride = DMODEL;
        }
        const int c4 = (t & 15) * 4;
        for (int rr = t >> 4; rr < 64; rr += 16) {
            float4 x = *(const float4*)(S + (size_t)(tile_r + rr) * R + tile_c + c4);
            Ls[rr][c4 + 0] = x.x; Ls[rr][c4 + 1] = x.y;
            Ls[rr][c4 + 2] = x.z; Ls[rr][c4 + 3] = x.w;
        }
        __syncthreads();
        const int r4 = (t & 15) * 4;
        for (int cc = t >> 4; cc < 64; cc += 16) {
            ushort4 o;
            o.x = f2bf(Ls[r4 + 0][cc] * scale); o.y = f2bf(Ls[r4 + 1][cc] * scale);
            o.z = f2bf(Ls[r4 + 2][cc] * scale); o.w = f2bf(Ls[r4 + 3][cc] * scale);
            *(ushort4*)(D + (size_t)(tile_c + cc) * ostride + tile_r + r4) = o;
        }
    }
}

// =====================================================================
// Projection GEMMs v10: 128x128 tiles (R6 geometry/epilogues), 768
// blocks XCD-swizzled, double-buffered (64 KB LDS, 2 blocks/CU).
// A operand read DIRECTLY from f32 q/k/v: issue-early reg-staged
// loads (step k+1 issued before compute of step k), pk2 cvt +
// ds_write after compute (T14 issue-early/write-late). B via gld_lds
// from prepped bf16 Wqt/Wkt/Wvt. At 2 waves/SIMD the 256-VGPR budget
// absorbs the ~32 staging registers (no R1-style spill).
// =====================================================================
__global__ __launch_bounds__(256) void proj_gemm_kernel(
    const float* __restrict__ qf32, const float* __restrict__ kf32,
    const float* __restrict__ vf32,
    const unsigned short* __restrict__ Wqt, const unsigned short* __restrict__ Wkt,
    const unsigned short* __restrict__ Wvt,
    unsigned short* __restrict__ qh, unsigned short* __restrict__ kh,
    unsigned short* __restrict__ vt)
{
    const int bid = blockIdx.x;
    const int sx = bid >> 3;
    const int mtg = (bid & 7) * 12 + (sx >> 3);
    const int z = mtg >> 5;
    const int m0 = (mtg & 31) * 128;
    const int n0 = (sx & 7) * 128;

    const float* Af = (z == 0) ? qf32 : (z == 1) ? kf32 : vf32;
    const unsigned short* Bt = (z == 0) ? Wqt : (z == 1) ? Wkt : Wvt;

    const int t = threadIdx.x, lane = t & 63, w = t >> 6;
    const int lg = lane >> 4, ln = lane & 15;
    const int wx = w & 1, wy = w >> 1;

    // As buf0 @0, As buf1 @8192, Bs buf0 @16384, Bs buf1 @24576 (shorts)
    __shared__ __align__(16) unsigned short SM[32768];

    // per-thread A chunk mapping (same XOR layout gld_lds produced)
    int an[4], ac[4];
    #pragma unroll
    for (int i = 0; i < 4; ++i) {
        const int s = i * 256 + t;
        an[i] = s >> 3;
        ac[i] = (s & 7) ^ (an[i] & 7);
    }

    f32x4 acc[4][4] = {};
    float4 ast[4][2];

    // ---- prologue: stage kk=0 ----
    #pragma unroll
    for (int i = 0; i < 4; ++i) {
        const float* src = Af + (size_t)(m0 + an[i]) * DMODEL + ac[i] * 8;
        ast[i][0] = *(const float4*)(src);
        ast[i][1] = *(const float4*)(src + 4);
    }
    #pragma unroll
    for (int i = 0; i < 4; ++i) {
        int s = (w * 4 + i) * 64 + lane;
        int n = s >> 3, c = (s & 7) ^ (n & 7);
        gld_lds16(Bt + (size_t)(n0 + n) * DMODEL + c * 8, SM + 16384 + (size_t)s * 8);
    }
    #pragma unroll
    for (int i = 0; i < 4; ++i) {
        uint4 val;
        val.x = pk2(ast[i][0].x, ast[i][0].y); val.y = pk2(ast[i][0].z, ast[i][0].w);
        val.z = pk2(ast[i][1].x, ast[i][1].y); val.w = pk2(ast[i][1].z, ast[i][1].w);
        *(uint4*)(SM + (size_t)(i * 256 + t) * 8) = val;
    }
    __syncthreads();

    for (int ki = 0; ki < 16; ++ki) {
        const int buf = ki & 1;

        // issue next step's loads before compute (latency hides under MFMA)
        if (ki < 15) {
            const int kk = (ki + 1) * 64;
            #pragma unroll
            for (int i = 0; i < 4; ++i) {
                const float* src = Af + (size_t)(m0 + an[i]) * DMODEL + kk + ac[i] * 8;
                ast[i][0] = *(const float4*)(src);
                ast[i][1] = *(const float4*)(src + 4);
            }
            #pragma unroll
            for (int i = 0; i < 4; ++i) {
                int s = (w * 4 + i) * 64 + lane;
                int n = s >> 3, c = (s & 7) ^ (n & 7);
                gld_lds16(Bt + (size_t)(n0 + n) * DMODEL + kk + c * 8,
                          SM + 16384 + (buf ^ 1) * 8192 + (size_t)s * 8);
            }
        }

        const unsigned short* Asb = SM + buf * 8192;
        const unsigned short* Bsb = SM + 16384 + buf * 8192;
        #pragma unroll
        for (int ks = 0; ks < 2; ++ks) {
            bf16x8 af[4], bf[4];
            #pragma unroll
            for (int rb = 0; rb < 4; ++rb) {
                int r = wy * 64 + rb * 16 + ln;
                af[rb] = *(const bf16x8*)(Asb + r * 64 + (((ks * 4 + lg) ^ (r & 7)) * 8));
            }
            #pragma unroll
            for (int nb = 0; nb < 4; ++nb) {
                int n = wx * 64 + nb * 16 + ln;
                bf[nb] = *(const bf16x8*)(Bsb + n * 64 + (((ks * 4 + lg) ^ (n & 7)) * 8));
            }
            #pragma unroll
            for (int rb = 0; rb < 4; ++rb)
                #pragma unroll
                for (int nb = 0; nb < 4; ++nb)
                    acc[rb][nb] = __builtin_amdgcn_mfma_f32_16x16x32_bf16(
                        af[rb], bf[nb], acc[rb][nb], 0, 0, 0);
        }

        // write-late: cvt + ds_write A(k+1) into the buffer just freed
        if (ki < 15) {
            unsigned short* Ad = SM + (buf ^ 1) * 8192;
            #pragma unroll
            for (int i = 0; i < 4; ++i) {
                uint4 val;
                val.x = pk2(ast[i][0].x, ast[i][0].y); val.y = pk2(ast[i][0].z, ast[i][0].w);
                val.z = pk2(ast[i][1].x, ast[i][1].y); val.w = pk2(ast[i][1].z, ast[i][1].w);
                *(uint4*)(Ad + (size_t)(i * 256 + t) * 8) = val;
            }
        }
        __syncthreads();   // drains vmcnt+lgkm: next buf fully staged
    }

    if (z < 2) {
        // stage [head][s 128][dh 64] then store 2x16KB contiguous runs
        unsigned short* Y = (z == 0) ? qh : kh;
        unsigned short* Ep = SM;
        #pragma unroll
        for (int rb = 0; rb < 4; ++rb)
            #pragma unroll
            for (int nb = 0; nb < 4; ++nb) {
                const int c_l = wx * 64 + nb * 16 + ln;
                const int base = ((c_l >> 6) << 13) + (c_l & 63);
                #pragma unroll
                for (int r = 0; r < 4; ++r) {
                    const int s_l = wy * 64 + rb * 16 + lg * 4 + r;
                    Ep[base + s_l * 64] = f2bf(acc[rb][nb][r]);
                }
            }
        __syncthreads();
        {
            const int head = t >> 7, r2 = t & 127;
            const unsigned short* src = Ep + head * 8192 + r2 * 64;
            unsigned short* dst = Y + ((size_t)((m0 >> 11) * NH + (n0 >> 6) + head) * SEQ
                                       + (m0 & (SEQ - 1)) + r2) * DHEAD;
            #pragma unroll
            for (int i = 0; i < 8; ++i)
                *(uint4*)(dst + i * 8) = *(const uint4*)(src + i * 8);
        }
    } else {
        // stage [head][dh 64][seq 128] (+pad 136) then store 128B dh-rows
        unsigned short* Ep = SM;
        #pragma unroll
        for (int rb = 0; rb < 4; ++rb)
            #pragma unroll
            for (int nb = 0; nb < 4; ++nb) {
                const int c_l = wx * 64 + nb * 16 + ln;
                const int seq0 = wy * 64 + rb * 16 + lg * 4;
                ushort4 o;
                o.x = f2bf(acc[rb][nb][0]); o.y = f2bf(acc[rb][nb][1]);
                o.z = f2bf(acc[rb][nb][2]); o.w = f2bf(acc[rb][nb][3]);
                *(ushort4*)(Ep + (c_l >> 6) * 8704 + (c_l & 63) * 136 + seq0) = o;
            }
        __syncthreads();
        {
            const int head = t >> 7, dh = (t >> 1) & 63, hf = t & 1;
            const unsigned short* src = Ep + head * 8704 + dh * 136 + hf * 64;
            unsigned short* dst = vt
                + ((size_t)((((m0 >> 11) << 4) + (n0 >> 6) + head) * DHEAD + dh) * SEQ
                   + (m0 & (SEQ - 1)) + hf * 64);
            #pragma unroll
            for (int i = 0; i < 8; ++i)
                *(uint4*)(dst + i * 8) = *(const uint4*)(src + i * 8);
        }
    }
}

// =====================================================================
// MFMA flash attention — unchanged from R8 (in-block K-split, 512
// blocks x 512 thr, 16 waves/CU, sbfe mask, setprio).
// =====================================================================
__global__ __launch_bounds__(512, 4) void attn_kernel(
    const unsigned short* __restrict__ qh, const unsigned short* __restrict__ kh,
    const unsigned short* __restrict__ vt, const unsigned long long* __restrict__ mpack,
    unsigned short* __restrict__ att)
{
    const int t = threadIdx.x, lane = t & 63;
    const int w8 = t >> 6;
    const int half = w8 >> 2, w = w8 & 3;
    const int th = t & 255;
    const int h = lane >> 5, lq = lane & 31;
    const int L = lq & 7, X = (lq >> 3) & 3;

    const int bid = blockIdx.x;
    const int r_ = bid >> 3;
    const int qt = r_ & 15;
    const int bh = (bid & 7) * 4 + (r_ >> 4);
    const int b = bh >> 4, hd = bh & 15;
    const int row0 = qt * 128;
    const int qrow = row0 + w * 32 + lq;
    const int kt0 = half * (SEQ / 2);

    __shared__ __align__(16) unsigned short SMEM[2 * 16384];
    unsigned short* Kh = SMEM + half * 16384;
    unsigned short* Vh = Kh + 8192;

    const unsigned short* Kb = kh + (size_t)bh * SEQ * DHEAD;
    const unsigned short* Vb = vt + (size_t)bh * DHEAD * SEQ;

    const unsigned short* Qb = qh + ((size_t)bh * SEQ + qrow) * DHEAD;
    bf16x8 qf[4];
    #pragma unroll
    for (int d = 0; d < 4; ++d) qf[d] = *(const bf16x8*)(Qb + d * 16 + h * 8);

    const unsigned long long* Mb = mpack + ((size_t)b * SEQ + qrow) * (SEQ / 64);

    int oK[2], oV[2], sL[2];
    #pragma unroll
    for (int i = 0; i < 2; ++i) {
        const int s = i * 256 + th;
        const int n = s >> 3, c = (s & 7) ^ (n & 7) ^ ((n >> 3) & 3);
        sL[i] = s * 8;
        oK[i] = n * DHEAD + c * 8;
        oV[i] = n * SEQ + c * 8;
    }

    f32x16 acc[2] = {};
    f32x16 lacc = {};
    bf16x8 ones;
    #pragma unroll
    for (int i = 0; i < 8; ++i) ones[i] = (short)0x3f80;   // bf16 1.0

    unsigned long long mw, mwn = 0;

    #pragma unroll
    for (int i = 0; i < 2; ++i)
        gld_lds16(Kb + (size_t)kt0 * DHEAD + oK[i], Kh + sL[i]);
    #pragma unroll
    for (int i = 0; i < 2; ++i)
        gld_lds16(Vb + (size_t)kt0 + oV[i], Vh + sL[i]);
    mw = Mb[half << 4];
    __syncthreads();

    for (int tix = 0; tix < 16; ++tix) {
        const int buf = tix & 1;

        if (tix < 15) {
            const int ktn = kt0 + (tix + 1) * 64;
            unsigned short* Kd = Kh + (buf ^ 1) * 4096;
            unsigned short* Vd = Vh + (buf ^ 1) * 4096;
            #pragma unroll
            for (int i = 0; i < 2; ++i)
                gld_lds16(Kb + (size_t)ktn * DHEAD + oK[i], Kd + sL[i]);
            #pragma unroll
            for (int i = 0; i < 2; ++i)
                gld_lds16(Vb + (size_t)ktn + oV[i], Vd + sL[i]);
            mwn = Mb[(half << 4) + tix + 1];
        }

        const unsigned short* Ksb = Kh + buf * 4096;
        const unsigned short* Vsb = Vh + buf * 4096;
        const unsigned long long mh_ = mw >> (h * 4);

        #pragma unroll
        for (int st = 0; st < 2; ++st) {
            f32x16 S = {};
            __builtin_amdgcn_s_setprio(1);
            #pragma unroll
            for (int d = 0; d < 4; ++d) {
                bf16x8 kf = *(const bf16x8*)(Ksb + (st * 32 + lq) * 64
                                             + (((d * 2 + h) ^ L ^ X) * 8));
                S = __builtin_amdgcn_mfma_f32_32x32x16_bf16(kf, qf[d], S, 0, 0, 0);
            }
            __builtin_amdgcn_s_setprio(0);
            const unsigned int wn = ~(unsigned int)(mh_ >> (32 * st));
            unsigned int pd[8];
            #pragma unroll
            for (int bb = 0; bb < 4; ++bb) {
                float e[4];
                #pragma unroll
                for (int rr = 0; rr < 4; ++rr) {
                    const int keep = __builtin_amdgcn_sbfe(wn, 8 * bb + rr, 1);
                    float ex = __builtin_amdgcn_exp2f(S[bb * 4 + rr]);
                    e[rr] = __uint_as_float(__float_as_uint(ex) & (unsigned int)keep);
                }
                pd[bb * 2 + 0] = __builtin_amdgcn_perm(
                    __float_as_uint(e[1]), __float_as_uint(e[0]), 0x07060302u);
                pd[bb * 2 + 1] = __builtin_amdgcn_perm(
                    __float_as_uint(e[3]), __float_as_uint(e[2]), 0x07060302u);
            }
            #pragma unroll
            for (int k2 = 0; k2 < 2; ++k2) {
                i32x4 pi = { (int)pd[4 * k2 + 0], (int)pd[4 * k2 + 1],
                             (int)pd[4 * k2 + 2], (int)pd[4 * k2 + 3] };
                bf16x8 pf = __builtin_bit_cast(bf16x8, pi);
                const int p0 = (((4 * st + 2 * k2) ^ L ^ X)) * 8;
                bf16x8 vf0, vf1;
                {
                    const unsigned short* vb_ = Vsb + lq * 64 + 4 * h;
                    bf16x4 a0 = *(const bf16x4*)(vb_ + p0);
                    bf16x4 a1 = *(const bf16x4*)(vb_ + (p0 ^ 8));
                    vf0 = __builtin_shufflevector(a0, a1, 0, 1, 2, 3, 4, 5, 6, 7);
                    const unsigned short* vc_ = vb_ + 32 * 64;
                    bf16x4 c0 = *(const bf16x4*)(vc_ + p0);
                    bf16x4 c1 = *(const bf16x4*)(vc_ + (p0 ^ 8));
                    vf1 = __builtin_shufflevector(c0, c1, 0, 1, 2, 3, 4, 5, 6, 7);
                }
                __builtin_amdgcn_s_setprio(1);
                lacc = __builtin_amdgcn_mfma_f32_32x32x16_bf16(ones, pf, lacc, 0, 0, 0);
                acc[0] = __builtin_amdgcn_mfma_f32_32x32x16_bf16(vf0, pf, acc[0], 0, 0, 0);
                acc[1] = __builtin_amdgcn_mfma_f32_32x32x16_bf16(vf1, pf, acc[1], 0, 0, 0);
                __builtin_amdgcn_s_setprio(0);
            }
        }

        mw = mwn;
        __syncthreads();
    }

    // ---- in-block combine: half 1 -> LDS, half 0 merges + stores ----
    const int rloc = w * 32 + lq;
    float* Osh = (float*)SMEM;             // [128][68] f32
    float* Lsh = (float*)SMEM + 128 * 68;  // [128] f32

    if (half == 1) {
        #pragma unroll
        for (int dt = 0; dt < 2; ++dt)
            #pragma unroll
            for (int g = 0; g < 4; ++g) {
                f32x4 v = { acc[dt][g * 4 + 0], acc[dt][g * 4 + 1],
                            acc[dt][g * 4 + 2], acc[dt][g * 4 + 3] };
                *(f32x4*)(Osh + rloc * 68 + dt * 32 + 8 * g + 4 * h) = v;
            }
        if (h == 0) Lsh[rloc] = lacc[0];
    }
    __syncthreads();
    if (half == 0) {
        const float linv = 1.0f / (lacc[0] + Lsh[rloc]);
        unsigned short* Ar = att + ((size_t)b * SEQ + qrow) * DMODEL + hd * DHEAD;
        #pragma unroll
        for (int dt = 0; dt < 2; ++dt)
            #pragma unroll
            for (int g = 0; g < 4; ++g) {
                const int dh0 = dt * 32 + 8 * g + 4 * h;
                f32x4 p = *(const f32x4*)(Osh + rloc * 68 + dh0);
                ushort4 o;
                o.x = f2bf((acc[dt][g * 4 + 0] + p[0]) * linv);
                o.y = f2bf((acc[dt][g * 4 + 1] + p[1]) * linv);
                o.z = f2bf((acc[dt][g * 4 + 2] + p[2]) * linv);
                o.w = f2bf((acc[dt][g * 4 + 3] + p[3]) * linv);
                *(ushort4*)(Ar + dh0) = o;
            }
    }
}

// =====================================================================
// Output GEMM — unchanged from R8 (64x128 dbuf, 48 KB LDS, 512 blocks).
// =====================================================================
__global__ __launch_bounds__(256) void out_gemm_kernel(
    const unsigned short* __restrict__ A, const unsigned short* __restrict__ Bt,
    float* __restrict__ C)
{
    const int bid = blockIdx.x;
    const int sx = bid >> 3;
    const int m0 = ((bid & 7) * 8 + (sx >> 3)) * 64;
    const int n0 = (sx & 7) * 128;

    const int t = threadIdx.x, lane = t & 63, w = t >> 6;
    const int lg = lane >> 4, ln = lane & 15;
    const int wx = w & 1, wy = w >> 1;

    __shared__ __align__(16) unsigned short SM[24576];

    f32x4 acc[2][4] = {};

    {
        unsigned short* Ad = SM;
        unsigned short* Bd = SM + 8192;
        #pragma unroll
        for (int i = 0; i < 4; ++i) {
            int s = (w * 4 + i) * 64 + lane;
            int n = s >> 3, c = (s & 7) ^ (n & 7);
            gld_lds16(Bt + (size_t)(n0 + n) * DMODEL + c * 8, Bd + (size_t)s * 8);
        }
        #pragma unroll
        for (int i = 0; i < 2; ++i) {
            int s = (w * 2 + i) * 64 + lane;
            int n = s >> 3, c = (s & 7) ^ (n & 7);
            gld_lds16(A + (size_t)(m0 + n) * DMODEL + c * 8, Ad + (size_t)s * 8);
        }
    }
    __syncthreads();

    for (int ki = 0; ki < 16; ++ki) {
        const int buf = ki & 1;

        if (ki < 15) {
            const int kk = (ki + 1) * 64;
            unsigned short* Ad = SM + (buf ^ 1) * 4096;
            unsigned short* Bd = SM + 8192 + (buf ^ 1) * 8192;
            #pragma unroll
            for (int i = 0; i < 4; ++i) {
                int s = (w * 4 + i) * 64 + lane;
                int n = s >> 3, c = (s & 7) ^ (n & 7);
                gld_lds16(Bt + (size_t)(n0 + n) * DMODEL + kk + c * 8, Bd + (size_t)s * 8);
            }
            #pragma unroll
            for (int i = 0; i < 2; ++i) {
                int s = (w * 2 + i) * 64 + lane;
                int n = s >> 3, c = (s & 7) ^ (n & 7);
                gld_lds16(A + (size_t)(m0 + n) * DMODEL + kk + c * 8, Ad + (size_t)s * 8);
            }
        }

        const unsigned short* Asb = SM + buf * 4096;
        const unsigned short* Bsb = SM + 8192 + buf * 8192;
        #pragma unroll
        for (int ks = 0; ks < 2; ++ks) {
            bf16x8 af[2], bf[4];
            #pragma unroll
            for (int rb = 0; rb < 2; ++rb) {
                int rr = wy * 32 + rb * 16 + ln;
                af[rb] = *(const bf16x8*)(Asb + rr * 64 + (((ks * 4 + lg) ^ (rr & 7)) * 8));
            }
            #pragma unroll
            for (int nb = 0; nb < 4; ++nb) {
                int n = wx * 64 + nb * 16 + ln;
                bf[nb] = *(const bf16x8*)(Bsb + n * 64 + (((ks * 4 + lg) ^ (n & 7)) * 8));
            }
            #pragma unroll
            for (int rb = 0; rb < 2; ++rb)
                #pragma unroll
                for (int nb = 0; nb < 4; ++nb)
                    acc[rb][nb] = __builtin_amdgcn_mfma_f32_16x16x32_bf16(
                        af[rb], bf[nb], acc[rb][nb], 0, 0, 0);
        }
        __syncthreads();
    }

    #pragma unroll
    for (int rb = 0; rb < 2; ++rb)
        #pragma unroll
        for (int nb = 0; nb < 4; ++nb)
            #pragma unroll
            for (int rr = 0; rr < 4; ++rr) {
                int grow = m0 + wy * 32 + rb * 16 + lg * 4 + rr;
                int gcol = n0 + wx * 64 + nb * 16 + ln;
                C[(size_t)grow * DMODEL + gcol] = acc[rb][nb][rr];
            }
}

extern "C" void kernel_launch(void* const* d_in, const int* in_sizes, int n_in,
                              void* d_out, int out_size, void* d_ws, size_t ws_size,
                              hipStream_t stream) {
    const float* q    = (const float*)d_in[0];
    const float* k    = (const float*)d_in[1];
    const float* v    = (const float*)d_in[2];
    const int*   mask = (const int*)  d_in[3];
    const float* Wq   = (const float*)d_in[4];
    const float* Wk   = (const float*)d_in[5];
    const float* Wv   = (const float*)d_in[6];
    const float* Wo   = (const float*)d_in[7];
    float* out = (float*)d_out;

    unsigned short* ws  = (unsigned short*)d_ws;
    const size_t n1 = (size_t)NB * NH * SEQ * DHEAD;      // 4,194,304 shorts
    const size_t nw = (size_t)NH * DHEAD * DMODEL;        // 1,048,576 shorts
    unsigned short* qh  = ws;
    unsigned short* kh  = qh + n1;
    unsigned short* vt  = kh + n1;                        // [bh][dh][seq]
    unsigned short* att = vt + n1;
    unsigned short* Wqt = att + n1;
    unsigned short* Wkt = Wqt + nw;
    unsigned short* Wvt = Wkt + nw;
    unsigned short* Wot = Wvt + nw;
    unsigned long long* mpack = (unsigned long long*)(Wot + nw);   // 1 MB

    prep_kernel<<<dim3(2048), 256, 0, stream>>>(
        mask, mpack, Wq, Wk, Wv, Wqt, Wkt, Wvt, Wo, Wot);
    proj_gemm_kernel<<<dim3(768), 256, 0, stream>>>(q, k, v, Wqt, Wkt, Wvt, qh, kh, vt);
    attn_kernel<<<dim3(512), 512, 0, stream>>>(qh, kh, vt, mpack, att);
    out_gemm_kernel<<<dim3(512), 256, 0, stream>>>(att, Wot, out);
}

// Round 10
// 248.159 us; speedup vs baseline: 1.1216x; 1.1216x over previous
//
#include <hip/hip_runtime.h>

#define NB 2
#define NH 16
#define SEQ 2048
#define DMODEL 1024
#define DHEAD 64
// 0.125 (1/sqrt(DH)) / ln(2): folded into Wq so softmax is a bare exp2
#define QSCALE 0.18033688f

typedef __attribute__((ext_vector_type(8))) short bf16x8;
typedef __attribute__((ext_vector_type(4))) short bf16x4;
typedef __attribute__((ext_vector_type(4))) float f32x4;
typedef __attribute__((ext_vector_type(16))) float f32x16;
typedef __attribute__((ext_vector_type(4))) int i32x4;

static __device__ __forceinline__ unsigned short f2bf(float f) {
    unsigned int u = __float_as_uint(f);
    u += 0x7fffu + ((u >> 16) & 1u);   // RNE
    return (unsigned short)(u >> 16);
}
static __device__ __forceinline__ unsigned int pk2(float lo, float hi) {
    return (unsigned int)f2bf(lo) | ((unsigned int)f2bf(hi) << 16);
}
static __device__ __forceinline__ void gld_lds16(const unsigned short* g, unsigned short* l) {
    __builtin_amdgcn_global_load_lds(
        (const __attribute__((address_space(1))) unsigned int*)g,
        (__attribute__((address_space(3))) unsigned int*)l, 16, 0, 0);
}

// =====================================================================
// Fused prep (one dispatch, 8192 blocks) — R8 version restored (the
// R9 f32-fusion into proj regressed: f32 staging doubled bytes and
// serialized cvt+ds_write into the K-step critical path).
//  [0,1024)     pack mask -> u64 bit words
//  [1024,1792)  Wq/Wk/Wv transpose+cvt (Wq scaled)
//  [1792,2048)  Wo transpose+cvt
//  [2048,8192)  q/k/v f32->bf16 copy
// =====================================================================
__global__ __launch_bounds__(256) void prep_kernel(
    const int* __restrict__ mask, unsigned long long* __restrict__ mpack,
    const float* __restrict__ Wq, const float* __restrict__ Wk, const float* __restrict__ Wv,
    unsigned short* __restrict__ Wqt, unsigned short* __restrict__ Wkt,
    unsigned short* __restrict__ Wvt,
    const float* __restrict__ Wo, unsigned short* __restrict__ Wot,
    const float* __restrict__ q, const float* __restrict__ k, const float* __restrict__ v,
    unsigned short* __restrict__ qb, unsigned short* __restrict__ kb,
    unsigned short* __restrict__ vb)
{
    __shared__ __align__(16) float Ls[64][65];
    const int bid = blockIdx.x, t = threadIdx.x;

    if (bid < 1024) {
        // ---- mask pack ----
        const int wave = bid * 4 + (t >> 6);
        const int lane = t & 63;
        const int* row = mask + (size_t)wave * SEQ;
        unsigned long long* orow = mpack + (size_t)wave * (SEQ / 64);
        for (int w = 0; w < SEQ / 64; ++w) {
            int m = row[w * 64 + lane];
            unsigned long long bits = __ballot(m != 0);
            if (lane == 0) orow[w] = bits;
        }
    } else if (bid < 2048) {
        // ---- weight transposes ----
        const float* S; unsigned short* D; float scale; int R, tile_r, tile_c, ostride;
        if (bid < 1792) {
            const int local = bid - 1024, z = local >> 4, sel = z >> 4, h = z & 15;
            S = (sel == 0 ? Wq : sel == 1 ? Wk : Wv) + (size_t)h * DMODEL * DHEAD;
            D = (sel == 0 ? Wqt : sel == 1 ? Wkt : Wvt) + (size_t)h * DMODEL * DHEAD;
            scale = (sel == 0) ? QSCALE : 1.0f;
            tile_r = (local & 15) * 64; tile_c = 0; R = DHEAD; ostride = DMODEL;
        } else {
            const int local = bid - 1792;
            S = Wo; D = Wot; scale = 1.0f;
            tile_c = (local & 15) * 64; tile_r = (local >> 4) * 64; R = DMODEL; ostride = DMODEL;
        }
        const int c4 = (t & 15) * 4;
        for (int rr = t >> 4; rr < 64; rr += 16) {
            float4 x = *(const float4*)(S + (size_t)(tile_r + rr) * R + tile_c + c4);
            Ls[rr][c4 + 0] = x.x; Ls[rr][c4 + 1] = x.y;
            Ls[rr][c4 + 2] = x.z; Ls[rr][c4 + 3] = x.w;
        }
        __syncthreads();
        const int r4 = (t & 15) * 4;
        for (int cc = t >> 4; cc < 64; cc += 16) {
            ushort4 o;
            o.x = f2bf(Ls[r4 + 0][cc] * scale); o.y = f2bf(Ls[r4 + 1][cc] * scale);
            o.z = f2bf(Ls[r4 + 2][cc] * scale); o.w = f2bf(Ls[r4 + 3][cc] * scale);
            *(ushort4*)(D + (size_t)(tile_c + cc) * ostride + tile_r + r4) = o;
        }
    } else {
        // ---- q/k/v f32 -> bf16 ----
        const int local = bid - 2048;
        const int z = local >> 11;
        const float* S = (z == 0) ? q : (z == 1) ? k : v;
        unsigned short* D = (z == 0) ? qb : (z == 1) ? kb : vb;
        const size_t i = ((size_t)(local & 2047) * 256 + t) * 8;
        float4 x0 = *(const float4*)(S + i);
        float4 x1 = *(const float4*)(S + i + 4);
        uint4 val;
        val.x = pk2(x0.x, x0.y); val.y = pk2(x0.z, x0.w);
        val.z = pk2(x1.x, x1.y); val.w = pk2(x1.z, x1.w);
        *(uint4*)(D + i) = val;
    }
}

// =====================================================================
// Projection GEMMs v11: 128x128 tiles (R6 geometry + LDS-staged
// epilogues) with the R8 issue-early double-buffered gld_lds loop,
// pure-bf16 operands. 768 blocks XCD-swizzled; LDS 64 KB (2 blocks/CU).
// 32 MFMA per 32 KB staged per K-step (2x R8's 64x128 density).
// =====================================================================
__global__ __launch_bounds__(256) void proj_gemm_kernel(
    const unsigned short* __restrict__ qb, const unsigned short* __restrict__ kb,
    const unsigned short* __restrict__ vb,
    const unsigned short* __restrict__ Wqt, const unsigned short* __restrict__ Wkt,
    const unsigned short* __restrict__ Wvt,
    unsigned short* __restrict__ qh, unsigned short* __restrict__ kh,
    unsigned short* __restrict__ vt)
{
    const int bid = blockIdx.x;
    const int sx = bid >> 3;
    const int mtg = (bid & 7) * 12 + (sx >> 3);
    const int z = mtg >> 5;
    const int m0 = (mtg & 31) * 128;
    const int n0 = (sx & 7) * 128;

    const unsigned short* A  = (z == 0) ? qb : (z == 1) ? kb : vb;
    const unsigned short* Bt = (z == 0) ? Wqt : (z == 1) ? Wkt : Wvt;

    const int t = threadIdx.x, lane = t & 63, w = t >> 6;
    const int lg = lane >> 4, ln = lane & 15;
    const int wx = w & 1, wy = w >> 1;

    // As buf0 @0, As buf1 @8192, Bs buf0 @16384, Bs buf1 @24576 (shorts)
    __shared__ __align__(16) unsigned short SM[32768];

    f32x4 acc[4][4] = {};

    // ---- prologue: stage kk=0 into buf0 ----
    #pragma unroll
    for (int i = 0; i < 4; ++i) {
        int s = i * 256 + t;
        int n = s >> 3, c = (s & 7) ^ (n & 7);
        gld_lds16(A + (size_t)(m0 + n) * DMODEL + c * 8, SM + (size_t)s * 8);
    }
    #pragma unroll
    for (int i = 0; i < 4; ++i) {
        int s = i * 256 + t;
        int n = s >> 3, c = (s & 7) ^ (n & 7);
        gld_lds16(Bt + (size_t)(n0 + n) * DMODEL + c * 8, SM + 16384 + (size_t)s * 8);
    }
    __syncthreads();

    for (int ki = 0; ki < 16; ++ki) {
        const int buf = ki & 1;

        // issue next K-step's DMA before compute — latency hides under MFMA
        if (ki < 15) {
            const int kk = (ki + 1) * 64;
            unsigned short* Ad = SM + (buf ^ 1) * 8192;
            unsigned short* Bd = SM + 16384 + (buf ^ 1) * 8192;
            #pragma unroll
            for (int i = 0; i < 4; ++i) {
                int s = i * 256 + t;
                int n = s >> 3, c = (s & 7) ^ (n & 7);
                gld_lds16(A + (size_t)(m0 + n) * DMODEL + kk + c * 8, Ad + (size_t)s * 8);
            }
            #pragma unroll
            for (int i = 0; i < 4; ++i) {
                int s = i * 256 + t;
                int n = s >> 3, c = (s & 7) ^ (n & 7);
                gld_lds16(Bt + (size_t)(n0 + n) * DMODEL + kk + c * 8, Bd + (size_t)s * 8);
            }
        }

        const unsigned short* Asb = SM + buf * 8192;
        const unsigned short* Bsb = SM + 16384 + buf * 8192;
        #pragma unroll
        for (int ks = 0; ks < 2; ++ks) {
            bf16x8 af[4], bf[4];
            #pragma unroll
            for (int rb = 0; rb < 4; ++rb) {
                int r = wy * 64 + rb * 16 + ln;
                af[rb] = *(const bf16x8*)(Asb + r * 64 + (((ks * 4 + lg) ^ (r & 7)) * 8));
            }
            #pragma unroll
            for (int nb = 0; nb < 4; ++nb) {
                int n = wx * 64 + nb * 16 + ln;
                bf[nb] = *(const bf16x8*)(Bsb + n * 64 + (((ks * 4 + lg) ^ (n & 7)) * 8));
            }
            #pragma unroll
            for (int rb = 0; rb < 4; ++rb)
                #pragma unroll
                for (int nb = 0; nb < 4; ++nb)
                    acc[rb][nb] = __builtin_amdgcn_mfma_f32_16x16x32_bf16(
                        af[rb], bf[nb], acc[rb][nb], 0, 0, 0);
        }
        __syncthreads();   // drains vmcnt(0): next buf staged; reads of buf done
    }

    if (z < 2) {
        // stage [head][s 128][dh 64] then store 2x16KB contiguous runs
        unsigned short* Y = (z == 0) ? qh : kh;
        unsigned short* Ep = SM;
        #pragma unroll
        for (int rb = 0; rb < 4; ++rb)
            #pragma unroll
            for (int nb = 0; nb < 4; ++nb) {
                const int c_l = wx * 64 + nb * 16 + ln;
                const int base = ((c_l >> 6) << 13) + (c_l & 63);
                #pragma unroll
                for (int r = 0; r < 4; ++r) {
                    const int s_l = wy * 64 + rb * 16 + lg * 4 + r;
                    Ep[base + s_l * 64] = f2bf(acc[rb][nb][r]);
                }
            }
        __syncthreads();
        {
            const int head = t >> 7, r2 = t & 127;
            const unsigned short* src = Ep + head * 8192 + r2 * 64;
            unsigned short* dst = Y + ((size_t)((m0 >> 11) * NH + (n0 >> 6) + head) * SEQ
                                       + (m0 & (SEQ - 1)) + r2) * DHEAD;
            #pragma unroll
            for (int i = 0; i < 8; ++i)
                *(uint4*)(dst + i * 8) = *(const uint4*)(src + i * 8);
        }
    } else {
        // stage [head][dh 64][seq 128] (+pad 136) then store 128B dh-rows
        unsigned short* Ep = SM;
        #pragma unroll
        for (int rb = 0; rb < 4; ++rb)
            #pragma unroll
            for (int nb = 0; nb < 4; ++nb) {
                const int c_l = wx * 64 + nb * 16 + ln;
                const int seq0 = wy * 64 + rb * 16 + lg * 4;
                ushort4 o;
                o.x = f2bf(acc[rb][nb][0]); o.y = f2bf(acc[rb][nb][1]);
                o.z = f2bf(acc[rb][nb][2]); o.w = f2bf(acc[rb][nb][3]);
                *(ushort4*)(Ep + (c_l >> 6) * 8704 + (c_l & 63) * 136 + seq0) = o;
            }
        __syncthreads();
        {
            const int head = t >> 7, dh = (t >> 1) & 63, hf = t & 1;
            const unsigned short* src = Ep + head * 8704 + dh * 136 + hf * 64;
            unsigned short* dst = vt
                + ((size_t)((((m0 >> 11) << 4) + (n0 >> 6) + head) * DHEAD + dh) * SEQ
                   + (m0 & (SEQ - 1)) + hf * 64);
            #pragma unroll
            for (int i = 0; i < 8; ++i)
                *(uint4*)(dst + i * 8) = *(const uint4*)(src + i * 8);
        }
    }
}

// =====================================================================
// MFMA flash attention — unchanged from R8 (in-block K-split, 512
// blocks x 512 thr, 16 waves/CU, sbfe mask, setprio).
// =====================================================================
__global__ __launch_bounds__(512, 4) void attn_kernel(
    const unsigned short* __restrict__ qh, const unsigned short* __restrict__ kh,
    const unsigned short* __restrict__ vt, const unsigned long long* __restrict__ mpack,
    unsigned short* __restrict__ att)
{
    const int t = threadIdx.x, lane = t & 63;
    const int w8 = t >> 6;
    const int half = w8 >> 2, w = w8 & 3;
    const int th = t & 255;
    const int h = lane >> 5, lq = lane & 31;
    const int L = lq & 7, X = (lq >> 3) & 3;

    const int bid = blockIdx.x;
    const int r_ = bid >> 3;
    const int qt = r_ & 15;
    const int bh = (bid & 7) * 4 + (r_ >> 4);
    const int b = bh >> 4, hd = bh & 15;
    const int row0 = qt * 128;
    const int qrow = row0 + w * 32 + lq;
    const int kt0 = half * (SEQ / 2);

    __shared__ __align__(16) unsigned short SMEM[2 * 16384];
    unsigned short* Kh = SMEM + half * 16384;
    unsigned short* Vh = Kh + 8192;

    const unsigned short* Kb = kh + (size_t)bh * SEQ * DHEAD;
    const unsigned short* Vb = vt + (size_t)bh * DHEAD * SEQ;

    const unsigned short* Qb = qh + ((size_t)bh * SEQ + qrow) * DHEAD;
    bf16x8 qf[4];
    #pragma unroll
    for (int d = 0; d < 4; ++d) qf[d] = *(const bf16x8*)(Qb + d * 16 + h * 8);

    const unsigned long long* Mb = mpack + ((size_t)b * SEQ + qrow) * (SEQ / 64);

    int oK[2], oV[2], sL[2];
    #pragma unroll
    for (int i = 0; i < 2; ++i) {
        const int s = i * 256 + th;
        const int n = s >> 3, c = (s & 7) ^ (n & 7) ^ ((n >> 3) & 3);
        sL[i] = s * 8;
        oK[i] = n * DHEAD + c * 8;
        oV[i] = n * SEQ + c * 8;
    }

    f32x16 acc[2] = {};
    f32x16 lacc = {};
    bf16x8 ones;
    #pragma unroll
    for (int i = 0; i < 8; ++i) ones[i] = (short)0x3f80;   // bf16 1.0

    unsigned long long mw, mwn = 0;

    #pragma unroll
    for (int i = 0; i < 2; ++i)
        gld_lds16(Kb + (size_t)kt0 * DHEAD + oK[i], Kh + sL[i]);
    #pragma unroll
    for (int i = 0; i < 2; ++i)
        gld_lds16(Vb + (size_t)kt0 + oV[i], Vh + sL[i]);
    mw = Mb[half << 4];
    __syncthreads();

    for (int tix = 0; tix < 16; ++tix) {
        const int buf = tix & 1;

        if (tix < 15) {
            const int ktn = kt0 + (tix + 1) * 64;
            unsigned short* Kd = Kh + (buf ^ 1) * 4096;
            unsigned short* Vd = Vh + (buf ^ 1) * 4096;
            #pragma unroll
            for (int i = 0; i < 2; ++i)
                gld_lds16(Kb + (size_t)ktn * DHEAD + oK[i], Kd + sL[i]);
            #pragma unroll
            for (int i = 0; i < 2; ++i)
                gld_lds16(Vb + (size_t)ktn + oV[i], Vd + sL[i]);
            mwn = Mb[(half << 4) + tix + 1];
        }

        const unsigned short* Ksb = Kh + buf * 4096;
        const unsigned short* Vsb = Vh + buf * 4096;
        const unsigned long long mh_ = mw >> (h * 4);

        #pragma unroll
        for (int st = 0; st < 2; ++st) {
            f32x16 S = {};
            __builtin_amdgcn_s_setprio(1);
            #pragma unroll
            for (int d = 0; d < 4; ++d) {
                bf16x8 kf = *(const bf16x8*)(Ksb + (st * 32 + lq) * 64
                                             + (((d * 2 + h) ^ L ^ X) * 8));
                S = __builtin_amdgcn_mfma_f32_32x32x16_bf16(kf, qf[d], S, 0, 0, 0);
            }
            __builtin_amdgcn_s_setprio(0);
            const unsigned int wn = ~(unsigned int)(mh_ >> (32 * st));
            unsigned int pd[8];
            #pragma unroll
            for (int bb = 0; bb < 4; ++bb) {
                float e[4];
                #pragma unroll
                for (int rr = 0; rr < 4; ++rr) {
                    const int keep = __builtin_amdgcn_sbfe(wn, 8 * bb + rr, 1);
                    float ex = __builtin_amdgcn_exp2f(S[bb * 4 + rr]);
                    e[rr] = __uint_as_float(__float_as_uint(ex) & (unsigned int)keep);
                }
                pd[bb * 2 + 0] = __builtin_amdgcn_perm(
                    __float_as_uint(e[1]), __float_as_uint(e[0]), 0x07060302u);
                pd[bb * 2 + 1] = __builtin_amdgcn_perm(
                    __float_as_uint(e[3]), __float_as_uint(e[2]), 0x07060302u);
            }
            #pragma unroll
            for (int k2 = 0; k2 < 2; ++k2) {
                i32x4 pi = { (int)pd[4 * k2 + 0], (int)pd[4 * k2 + 1],
                             (int)pd[4 * k2 + 2], (int)pd[4 * k2 + 3] };
                bf16x8 pf = __builtin_bit_cast(bf16x8, pi);
                const int p0 = (((4 * st + 2 * k2) ^ L ^ X)) * 8;
                bf16x8 vf0, vf1;
                {
                    const unsigned short* vb_ = Vsb + lq * 64 + 4 * h;
                    bf16x4 a0 = *(const bf16x4*)(vb_ + p0);
                    bf16x4 a1 = *(const bf16x4*)(vb_ + (p0 ^ 8));
                    vf0 = __builtin_shufflevector(a0, a1, 0, 1, 2, 3, 4, 5, 6, 7);
                    const unsigned short* vc_ = vb_ + 32 * 64;
                    bf16x4 c0 = *(const bf16x4*)(vc_ + p0);
                    bf16x4 c1 = *(const bf16x4*)(vc_ + (p0 ^ 8));
                    vf1 = __builtin_shufflevector(c0, c1, 0, 1, 2, 3, 4, 5, 6, 7);
                }
                __builtin_amdgcn_s_setprio(1);
                lacc = __builtin_amdgcn_mfma_f32_32x32x16_bf16(ones, pf, lacc, 0, 0, 0);
                acc[0] = __builtin_amdgcn_mfma_f32_32x32x16_bf16(vf0, pf, acc[0], 0, 0, 0);
                acc[1] = __builtin_amdgcn_mfma_f32_32x32x16_bf16(vf1, pf, acc[1], 0, 0, 0);
                __builtin_amdgcn_s_setprio(0);
            }
        }

        mw = mwn;
        __syncthreads();
    }

    // ---- in-block combine: half 1 -> LDS, half 0 merges + stores ----
    const int rloc = w * 32 + lq;
    float* Osh = (float*)SMEM;             // [128][68] f32
    float* Lsh = (float*)SMEM + 128 * 68;  // [128] f32

    if (half == 1) {
        #pragma unroll
        for (int dt = 0; dt < 2; ++dt)
            #pragma unroll
            for (int g = 0; g < 4; ++g) {
                f32x4 v = { acc[dt][g * 4 + 0], acc[dt][g * 4 + 1],
                            acc[dt][g * 4 + 2], acc[dt][g * 4 + 3] };
                *(f32x4*)(Osh + rloc * 68 + dt * 32 + 8 * g + 4 * h) = v;
            }
        if (h == 0) Lsh[rloc] = lacc[0];
    }
    __syncthreads();
    if (half == 0) {
        const float linv = 1.0f / (lacc[0] + Lsh[rloc]);
        unsigned short* Ar = att + ((size_t)b * SEQ + qrow) * DMODEL + hd * DHEAD;
        #pragma unroll
        for (int dt = 0; dt < 2; ++dt)
            #pragma unroll
            for (int g = 0; g < 4; ++g) {
                const int dh0 = dt * 32 + 8 * g + 4 * h;
                f32x4 p = *(const f32x4*)(Osh + rloc * 68 + dh0);
                ushort4 o;
                o.x = f2bf((acc[dt][g * 4 + 0] + p[0]) * linv);
                o.y = f2bf((acc[dt][g * 4 + 1] + p[1]) * linv);
                o.z = f2bf((acc[dt][g * 4 + 2] + p[2]) * linv);
                o.w = f2bf((acc[dt][g * 4 + 3] + p[3]) * linv);
                *(ushort4*)(Ar + dh0) = o;
            }
    }
}

// =====================================================================
// Output GEMM — unchanged from R8 (64x128 dbuf, 48 KB LDS, 512 blocks).
// =====================================================================
__global__ __launch_bounds__(256) void out_gemm_kernel(
    const unsigned short* __restrict__ A, const unsigned short* __restrict__ Bt,
    float* __restrict__ C)
{
    const int bid = blockIdx.x;
    const int sx = bid >> 3;
    const int m0 = ((bid & 7) * 8 + (sx >> 3)) * 64;
    const int n0 = (sx & 7) * 128;

    const int t = threadIdx.x, lane = t & 63, w = t >> 6;
    const int lg = lane >> 4, ln = lane & 15;
    const int wx = w & 1, wy = w >> 1;

    __shared__ __align__(16) unsigned short SM[24576];

    f32x4 acc[2][4] = {};

    {
        unsigned short* Ad = SM;
        unsigned short* Bd = SM + 8192;
        #pragma unroll
        for (int i = 0; i < 4; ++i) {
            int s = (w * 4 + i) * 64 + lane;
            int n = s >> 3, c = (s & 7) ^ (n & 7);
            gld_lds16(Bt + (size_t)(n0 + n) * DMODEL + c * 8, Bd + (size_t)s * 8);
        }
        #pragma unroll
        for (int i = 0; i < 2; ++i) {
            int s = (w * 2 + i) * 64 + lane;
            int n = s >> 3, c = (s & 7) ^ (n & 7);
            gld_lds16(A + (size_t)(m0 + n) * DMODEL + c * 8, Ad + (size_t)s * 8);
        }
    }
    __syncthreads();

    for (int ki = 0; ki < 16; ++ki) {
        const int buf = ki & 1;

        if (ki < 15) {
            const int kk = (ki + 1) * 64;
            unsigned short* Ad = SM + (buf ^ 1) * 4096;
            unsigned short* Bd = SM + 8192 + (buf ^ 1) * 8192;
            #pragma unroll
            for (int i = 0; i < 4; ++i) {
                int s = (w * 4 + i) * 64 + lane;
                int n = s >> 3, c = (s & 7) ^ (n & 7);
                gld_lds16(Bt + (size_t)(n0 + n) * DMODEL + kk + c * 8, Bd + (size_t)s * 8);
            }
            #pragma unroll
            for (int i = 0; i < 2; ++i) {
                int s = (w * 2 + i) * 64 + lane;
                int n = s >> 3, c = (s & 7) ^ (n & 7);
                gld_lds16(A + (size_t)(m0 + n) * DMODEL + kk + c * 8, Ad + (size_t)s * 8);
            }
        }

        const unsigned short* Asb = SM + buf * 4096;
        const unsigned short* Bsb = SM + 8192 + buf * 8192;
        #pragma unroll
        for (int ks = 0; ks < 2; ++ks) {
            bf16x8 af[2], bf[4];
            #pragma unroll
            for (int rb = 0; rb < 2; ++rb) {
                int rr = wy * 32 + rb * 16 + ln;
                af[rb] = *(const bf16x8*)(Asb + rr * 64 + (((ks * 4 + lg) ^ (rr & 7)) * 8));
            }
            #pragma unroll
            for (int nb = 0; nb < 4; ++nb) {
                int n = wx * 64 + nb * 16 + ln;
                bf[nb] = *(const bf16x8*)(Bsb + n * 64 + (((ks * 4 + lg) ^ (n & 7)) * 8));
            }
            #pragma unroll
            for (int rb = 0; rb < 2; ++rb)
                #pragma unroll
                for (int nb = 0; nb < 4; ++nb)
                    acc[rb][nb] = __builtin_amdgcn_mfma_f32_16x16x32_bf16(
                        af[rb], bf[nb], acc[rb][nb], 0, 0, 0);
        }
        __syncthreads();
    }

    #pragma unroll
    for (int rb = 0; rb < 2; ++rb)
        #pragma unroll
        for (int nb = 0; nb < 4; ++nb)
            #pragma unroll
            for (int rr = 0; rr < 4; ++rr) {
                int grow = m0 + wy * 32 + rb * 16 + lg * 4 + rr;
                int gcol = n0 + wx * 64 + nb * 16 + ln;
                C[(size_t)grow * DMODEL + gcol] = acc[rb][nb][rr];
            }
}

extern "C" void kernel_launch(void* const* d_in, const int* in_sizes, int n_in,
                              void* d_out, int out_size, void* d_ws, size_t ws_size,
                              hipStream_t stream) {
    const float* q    = (const float*)d_in[0];
    const float* k    = (const float*)d_in[1];
    const float* v    = (const float*)d_in[2];
    const int*   mask = (const int*)  d_in[3];
    const float* Wq   = (const float*)d_in[4];
    const float* Wk   = (const float*)d_in[5];
    const float* Wv   = (const float*)d_in[6];
    const float* Wo   = (const float*)d_in[7];
    float* out = (float*)d_out;

    unsigned short* ws  = (unsigned short*)d_ws;
    const size_t n1 = (size_t)NB * NH * SEQ * DHEAD;      // 4,194,304 shorts
    const size_t nw = (size_t)NH * DHEAD * DMODEL;        // 1,048,576 shorts
    unsigned short* qh  = ws;
    unsigned short* kh  = qh + n1;
    unsigned short* vt  = kh + n1;                        // [bh][dh][seq]
    unsigned short* att = vt + n1;
    unsigned short* Wqt = att + n1;
    unsigned short* Wkt = Wqt + nw;
    unsigned short* Wvt = Wkt + nw;
    unsigned short* Wot = Wvt + nw;
    unsigned long long* mpack = (unsigned long long*)(Wot + nw);   // 1 MB
    unsigned short* qb = (unsigned short*)(mpack + (size_t)NB * SEQ * (SEQ / 64));
    unsigned short* kb = qb + n1;
    unsigned short* vb = kb + n1;

    prep_kernel<<<dim3(8192), 256, 0, stream>>>(
        mask, mpack, Wq, Wk, Wv, Wqt, Wkt, Wvt, Wo, Wot, q, k, v, qb, kb, vb);
    proj_gemm_kernel<<<dim3(768), 256, 0, stream>>>(qb, kb, vb, Wqt, Wkt, Wvt, qh, kh, vt);
    attn_kernel<<<dim3(512), 512, 0, stream>>>(qh, kh, vt, mpack, att);
    out_gemm_kernel<<<dim3(512), 256, 0, stream>>>(att, Wot, out);
}

// Round 12
// 235.217 us; speedup vs baseline: 1.1834x; 1.0550x over previous
//
#include <hip/hip_runtime.h>

#define NB 2
#define NH 16
#define SEQ 2048
#define DMODEL 1024
#define DHEAD 64
// 0.125 (1/sqrt(DH)) / ln(2): folded into Wq so softmax is a bare exp2
#define QSCALE 0.18033688f

typedef __attribute__((ext_vector_type(8))) short bf16x8;
typedef __attribute__((ext_vector_type(4))) short bf16x4;
typedef __attribute__((ext_vector_type(4))) float f32x4;
typedef __attribute__((ext_vector_type(16))) float f32x16;
typedef __attribute__((ext_vector_type(4))) int i32x4;

static __device__ __forceinline__ unsigned short f2bf(float f) {
    unsigned int u = __float_as_uint(f);
    u += 0x7fffu + ((u >> 16) & 1u);   // RNE
    return (unsigned short)(u >> 16);
}
static __device__ __forceinline__ unsigned int pk2(float lo, float hi) {
    return (unsigned int)f2bf(lo) | ((unsigned int)f2bf(hi) << 16);
}
static __device__ __forceinline__ void gld_lds16(const unsigned short* g, unsigned short* l) {
    __builtin_amdgcn_global_load_lds(
        (const __attribute__((address_space(1))) unsigned int*)g,
        (__attribute__((address_space(3))) unsigned int*)l, 16, 0, 0);
}

// =====================================================================
// Fused prep (one dispatch, 8192 blocks) — R8 structure; v12b adds
// non-temporal loads on all READ-ONCE streams (mask, q/k/v f32,
// weight f32) via ext_vector f32x4 (the HIP float4 struct type is
// rejected by __builtin_nontemporal_load — R11 compile fix).
//  [0,1024)     pack mask -> u64 bit words
//  [1024,1792)  Wq/Wk/Wv transpose+cvt (Wq scaled)
//  [1792,2048)  Wo transpose+cvt
//  [2048,8192)  q/k/v f32->bf16 copy
// =====================================================================
__global__ __launch_bounds__(256) void prep_kernel(
    const int* __restrict__ mask, unsigned long long* __restrict__ mpack,
    const float* __restrict__ Wq, const float* __restrict__ Wk, const float* __restrict__ Wv,
    unsigned short* __restrict__ Wqt, unsigned short* __restrict__ Wkt,
    unsigned short* __restrict__ Wvt,
    const float* __restrict__ Wo, unsigned short* __restrict__ Wot,
    const float* __restrict__ q, const float* __restrict__ k, const float* __restrict__ v,
    unsigned short* __restrict__ qb, unsigned short* __restrict__ kb,
    unsigned short* __restrict__ vb)
{
    __shared__ __align__(16) float Ls[64][65];
    const int bid = blockIdx.x, t = threadIdx.x;

    if (bid < 1024) {
        // ---- mask pack (read-once: NT loads) ----
        const int wave = bid * 4 + (t >> 6);
        const int lane = t & 63;
        const int* row = mask + (size_t)wave * SEQ;
        unsigned long long* orow = mpack + (size_t)wave * (SEQ / 64);
        for (int w = 0; w < SEQ / 64; ++w) {
            int m = __builtin_nontemporal_load(row + w * 64 + lane);
            unsigned long long bits = __ballot(m != 0);
            if (lane == 0) orow[w] = bits;
        }
    } else if (bid < 2048) {
        // ---- weight transposes (read-once: NT loads) ----
        const float* S; unsigned short* D; float scale; int R, tile_r, tile_c, ostride;
        if (bid < 1792) {
            const int local = bid - 1024, z = local >> 4, sel = z >> 4, h = z & 15;
            S = (sel == 0 ? Wq : sel == 1 ? Wk : Wv) + (size_t)h * DMODEL * DHEAD;
            D = (sel == 0 ? Wqt : sel == 1 ? Wkt : Wvt) + (size_t)h * DMODEL * DHEAD;
            scale = (sel == 0) ? QSCALE : 1.0f;
            tile_r = (local & 15) * 64; tile_c = 0; R = DHEAD; ostride = DMODEL;
        } else {
            const int local = bid - 1792;
            S = Wo; D = Wot; scale = 1.0f;
            tile_c = (local & 15) * 64; tile_r = (local >> 4) * 64; R = DMODEL; ostride = DMODEL;
        }
        const int c4 = (t & 15) * 4;
        for (int rr = t >> 4; rr < 64; rr += 16) {
            f32x4 x = __builtin_nontemporal_load(
                (const f32x4*)(S + (size_t)(tile_r + rr) * R + tile_c + c4));
            Ls[rr][c4 + 0] = x[0]; Ls[rr][c4 + 1] = x[1];
            Ls[rr][c4 + 2] = x[2]; Ls[rr][c4 + 3] = x[3];
        }
        __syncthreads();
        const int r4 = (t & 15) * 4;
        for (int cc = t >> 4; cc < 64; cc += 16) {
            ushort4 o;
            o.x = f2bf(Ls[r4 + 0][cc] * scale); o.y = f2bf(Ls[r4 + 1][cc] * scale);
            o.z = f2bf(Ls[r4 + 2][cc] * scale); o.w = f2bf(Ls[r4 + 3][cc] * scale);
            *(ushort4*)(D + (size_t)(tile_c + cc) * ostride + tile_r + r4) = o;
        }
    } else {
        // ---- q/k/v f32 -> bf16 (read-once: NT loads; bf16 out stays in L2) ----
        const int local = bid - 2048;
        const int z = local >> 11;
        const float* S = (z == 0) ? q : (z == 1) ? k : v;
        unsigned short* D = (z == 0) ? qb : (z == 1) ? kb : vb;
        const size_t i = ((size_t)(local & 2047) * 256 + t) * 8;
        f32x4 x0 = __builtin_nontemporal_load((const f32x4*)(S + i));
        f32x4 x1 = __builtin_nontemporal_load((const f32x4*)(S + i + 4));
        uint4 val;
        val.x = pk2(x0[0], x0[1]); val.y = pk2(x0[2], x0[3]);
        val.z = pk2(x1[0], x1[1]); val.w = pk2(x1[2], x1[3]);
        *(uint4*)(D + i) = val;
    }
}

// =====================================================================
// Projection GEMMs — R8 champion version: 64x128 tiles, 1536 virtual
// tiles = 768 blocks x 2; issue-early double-buffered gld_lds;
// 48 KB LDS -> 3 blocks/CU.
// =====================================================================
__global__ __launch_bounds__(256) void proj_gemm_kernel(
    const unsigned short* __restrict__ qb, const unsigned short* __restrict__ kb,
    const unsigned short* __restrict__ vb,
    const unsigned short* __restrict__ Wqt, const unsigned short* __restrict__ Wkt,
    const unsigned short* __restrict__ Wvt,
    unsigned short* __restrict__ qh, unsigned short* __restrict__ kh,
    unsigned short* __restrict__ vt)
{
    const int t = threadIdx.x, lane = t & 63, w = t >> 6;
    const int lg = lane >> 4, ln = lane & 15;
    const int wx = w & 1, wy = w >> 1;

    // As[2] @0/4096, Bs[2] @8192/16384 (shorts). 48 KB total.
    __shared__ __align__(16) unsigned short SM[24576];

    #pragma unroll 1
    for (int vi = 0; vi < 2; ++vi) {
        const int vti = blockIdx.x + vi * 768;     // [0,1536)
        const int z = vti >> 9;
        const int r = vti & 511;
        const int m0 = ((r & 7) * 8 + (r >> 6)) * 64;
        const int n0 = ((r >> 3) & 7) * 128;

        const unsigned short* A  = (z == 0) ? qb : (z == 1) ? kb : vb;
        const unsigned short* Bt = (z == 0) ? Wqt : (z == 1) ? Wkt : Wvt;

        f32x4 acc[2][4] = {};

        // ---- prologue: stage kk=0 into buf0 ----
        {
            unsigned short* Ad = SM;
            unsigned short* Bd = SM + 8192;
            #pragma unroll
            for (int i = 0; i < 4; ++i) {
                int s = (w * 4 + i) * 64 + lane;
                int n = s >> 3, c = (s & 7) ^ (n & 7);
                gld_lds16(Bt + (size_t)(n0 + n) * DMODEL + c * 8, Bd + (size_t)s * 8);
            }
            #pragma unroll
            for (int i = 0; i < 2; ++i) {
                int s = (w * 2 + i) * 64 + lane;
                int n = s >> 3, c = (s & 7) ^ (n & 7);
                gld_lds16(A + (size_t)(m0 + n) * DMODEL + c * 8, Ad + (size_t)s * 8);
            }
        }
        __syncthreads();

        for (int ki = 0; ki < 16; ++ki) {
            const int buf = ki & 1;

            // issue next K-step's DMA before compute — latency hides under MFMA
            if (ki < 15) {
                const int kk = (ki + 1) * 64;
                unsigned short* Ad = SM + (buf ^ 1) * 4096;
                unsigned short* Bd = SM + 8192 + (buf ^ 1) * 8192;
                #pragma unroll
                for (int i = 0; i < 4; ++i) {
                    int s = (w * 4 + i) * 64 + lane;
                    int n = s >> 3, c = (s & 7) ^ (n & 7);
                    gld_lds16(Bt + (size_t)(n0 + n) * DMODEL + kk + c * 8, Bd + (size_t)s * 8);
                }
                #pragma unroll
                for (int i = 0; i < 2; ++i) {
                    int s = (w * 2 + i) * 64 + lane;
                    int n = s >> 3, c = (s & 7) ^ (n & 7);
                    gld_lds16(A + (size_t)(m0 + n) * DMODEL + kk + c * 8, Ad + (size_t)s * 8);
                }
            }

            const unsigned short* Asb = SM + buf * 4096;
            const unsigned short* Bsb = SM + 8192 + buf * 8192;
            #pragma unroll
            for (int ks = 0; ks < 2; ++ks) {
                bf16x8 af[2], bf[4];
                #pragma unroll
                for (int rb = 0; rb < 2; ++rb) {
                    int rr = wy * 32 + rb * 16 + ln;
                    af[rb] = *(const bf16x8*)(Asb + rr * 64 + (((ks * 4 + lg) ^ (rr & 7)) * 8));
                }
                #pragma unroll
                for (int nb = 0; nb < 4; ++nb) {
                    int n = wx * 64 + nb * 16 + ln;
                    bf[nb] = *(const bf16x8*)(Bsb + n * 64 + (((ks * 4 + lg) ^ (n & 7)) * 8));
                }
                #pragma unroll
                for (int rb = 0; rb < 2; ++rb)
                    #pragma unroll
                    for (int nb = 0; nb < 4; ++nb)
                        acc[rb][nb] = __builtin_amdgcn_mfma_f32_16x16x32_bf16(
                            af[rb], bf[nb], acc[rb][nb], 0, 0, 0);
            }
            __syncthreads();   // drains vmcnt(0): next buf staged; reads of buf done
        }

        // ---- epilogue: scatter stores (register -> global, no LDS) ----
        if (z < 2) {
            unsigned short* Y = (z == 0) ? qh : kh;
            #pragma unroll
            for (int rb = 0; rb < 2; ++rb)
                #pragma unroll
                for (int nb = 0; nb < 4; ++nb)
                    #pragma unroll
                    for (int rr = 0; rr < 4; ++rr) {
                        int grow = m0 + wy * 32 + rb * 16 + lg * 4 + rr;
                        int gcol = n0 + wx * 64 + nb * 16 + ln;
                        size_t idx = ((size_t)((grow >> 11) * NH + (gcol >> 6)) * SEQ
                                      + (grow & (SEQ - 1))) * DHEAD + (gcol & 63);
                        Y[idx] = f2bf(acc[rb][nb][rr]);
                    }
        } else {
            #pragma unroll
            for (int rb = 0; rb < 2; ++rb)
                #pragma unroll
                for (int nb = 0; nb < 4; ++nb) {
                    int grow0 = m0 + wy * 32 + rb * 16 + lg * 4;
                    int gcol  = n0 + wx * 64 + nb * 16 + ln;
                    int bh = ((grow0 >> 11) << 4) + (gcol >> 6);
                    ushort4 st;
                    st.x = f2bf(acc[rb][nb][0]); st.y = f2bf(acc[rb][nb][1]);
                    st.z = f2bf(acc[rb][nb][2]); st.w = f2bf(acc[rb][nb][3]);
                    *(ushort4*)(vt + ((size_t)bh * DHEAD + (gcol & 63)) * SEQ
                                     + (grow0 & (SEQ - 1))) = st;
                }
        }
    }
}

// =====================================================================
// MFMA flash attention — unchanged from R8 (in-block K-split, 512
// blocks x 512 thr, 16 waves/CU, sbfe mask, setprio).
// =====================================================================
__global__ __launch_bounds__(512, 4) void attn_kernel(
    const unsigned short* __restrict__ qh, const unsigned short* __restrict__ kh,
    const unsigned short* __restrict__ vt, const unsigned long long* __restrict__ mpack,
    unsigned short* __restrict__ att)
{
    const int t = threadIdx.x, lane = t & 63;
    const int w8 = t >> 6;
    const int half = w8 >> 2, w = w8 & 3;
    const int th = t & 255;
    const int h = lane >> 5, lq = lane & 31;
    const int L = lq & 7, X = (lq >> 3) & 3;

    const int bid = blockIdx.x;
    const int r_ = bid >> 3;
    const int qt = r_ & 15;
    const int bh = (bid & 7) * 4 + (r_ >> 4);
    const int b = bh >> 4, hd = bh & 15;
    const int row0 = qt * 128;
    const int qrow = row0 + w * 32 + lq;
    const int kt0 = half * (SEQ / 2);

    __shared__ __align__(16) unsigned short SMEM[2 * 16384];
    unsigned short* Kh = SMEM + half * 16384;
    unsigned short* Vh = Kh + 8192;

    const unsigned short* Kb = kh + (size_t)bh * SEQ * DHEAD;
    const unsigned short* Vb = vt + (size_t)bh * DHEAD * SEQ;

    const unsigned short* Qb = qh + ((size_t)bh * SEQ + qrow) * DHEAD;
    bf16x8 qf[4];
    #pragma unroll
    for (int d = 0; d < 4; ++d) qf[d] = *(const bf16x8*)(Qb + d * 16 + h * 8);

    const unsigned long long* Mb = mpack + ((size_t)b * SEQ + qrow) * (SEQ / 64);

    int oK[2], oV[2], sL[2];
    #pragma unroll
    for (int i = 0; i < 2; ++i) {
        const int s = i * 256 + th;
        const int n = s >> 3, c = (s & 7) ^ (n & 7) ^ ((n >> 3) & 3);
        sL[i] = s * 8;
        oK[i] = n * DHEAD + c * 8;
        oV[i] = n * SEQ + c * 8;
    }

    f32x16 acc[2] = {};
    f32x16 lacc = {};
    bf16x8 ones;
    #pragma unroll
    for (int i = 0; i < 8; ++i) ones[i] = (short)0x3f80;   // bf16 1.0

    unsigned long long mw, mwn = 0;

    #pragma unroll
    for (int i = 0; i < 2; ++i)
        gld_lds16(Kb + (size_t)kt0 * DHEAD + oK[i], Kh + sL[i]);
    #pragma unroll
    for (int i = 0; i < 2; ++i)
        gld_lds16(Vb + (size_t)kt0 + oV[i], Vh + sL[i]);
    mw = Mb[half << 4];
    __syncthreads();

    for (int tix = 0; tix < 16; ++tix) {
        const int buf = tix & 1;

        if (tix < 15) {
            const int ktn = kt0 + (tix + 1) * 64;
            unsigned short* Kd = Kh + (buf ^ 1) * 4096;
            unsigned short* Vd = Vh + (buf ^ 1) * 4096;
            #pragma unroll
            for (int i = 0; i < 2; ++i)
                gld_lds16(Kb + (size_t)ktn * DHEAD + oK[i], Kd + sL[i]);
            #pragma unroll
            for (int i = 0; i < 2; ++i)
                gld_lds16(Vb + (size_t)ktn + oV[i], Vd + sL[i]);
            mwn = Mb[(half << 4) + tix + 1];
        }

        const unsigned short* Ksb = Kh + buf * 4096;
        const unsigned short* Vsb = Vh + buf * 4096;
        const unsigned long long mh_ = mw >> (h * 4);

        #pragma unroll
        for (int st = 0; st < 2; ++st) {
            f32x16 S = {};
            __builtin_amdgcn_s_setprio(1);
            #pragma unroll
            for (int d = 0; d < 4; ++d) {
                bf16x8 kf = *(const bf16x8*)(Ksb + (st * 32 + lq) * 64
                                             + (((d * 2 + h) ^ L ^ X) * 8));
                S = __builtin_amdgcn_mfma_f32_32x32x16_bf16(kf, qf[d], S, 0, 0, 0);
            }
            __builtin_amdgcn_s_setprio(0);
            const unsigned int wn = ~(unsigned int)(mh_ >> (32 * st));
            unsigned int pd[8];
            #pragma unroll
            for (int bb = 0; bb < 4; ++bb) {
                float e[4];
                #pragma unroll
                for (int rr = 0; rr < 4; ++rr) {
                    const int keep = __builtin_amdgcn_sbfe(wn, 8 * bb + rr, 1);
                    float ex = __builtin_amdgcn_exp2f(S[bb * 4 + rr]);
                    e[rr] = __uint_as_float(__float_as_uint(ex) & (unsigned int)keep);
                }
                pd[bb * 2 + 0] = __builtin_amdgcn_perm(
                    __float_as_uint(e[1]), __float_as_uint(e[0]), 0x07060302u);
                pd[bb * 2 + 1] = __builtin_amdgcn_perm(
                    __float_as_uint(e[3]), __float_as_uint(e[2]), 0x07060302u);
            }
            #pragma unroll
            for (int k2 = 0; k2 < 2; ++k2) {
                i32x4 pi = { (int)pd[4 * k2 + 0], (int)pd[4 * k2 + 1],
                             (int)pd[4 * k2 + 2], (int)pd[4 * k2 + 3] };
                bf16x8 pf = __builtin_bit_cast(bf16x8, pi);
                const int p0 = (((4 * st + 2 * k2) ^ L ^ X)) * 8;
                bf16x8 vf0, vf1;
                {
                    const unsigned short* vb_ = Vsb + lq * 64 + 4 * h;
                    bf16x4 a0 = *(const bf16x4*)(vb_ + p0);
                    bf16x4 a1 = *(const bf16x4*)(vb_ + (p0 ^ 8));
                    vf0 = __builtin_shufflevector(a0, a1, 0, 1, 2, 3, 4, 5, 6, 7);
                    const unsigned short* vc_ = vb_ + 32 * 64;
                    bf16x4 c0 = *(const bf16x4*)(vc_ + p0);
                    bf16x4 c1 = *(const bf16x4*)(vc_ + (p0 ^ 8));
                    vf1 = __builtin_shufflevector(c0, c1, 0, 1, 2, 3, 4, 5, 6, 7);
                }
                __builtin_amdgcn_s_setprio(1);
                lacc = __builtin_amdgcn_mfma_f32_32x32x16_bf16(ones, pf, lacc, 0, 0, 0);
                acc[0] = __builtin_amdgcn_mfma_f32_32x32x16_bf16(vf0, pf, acc[0], 0, 0, 0);
                acc[1] = __builtin_amdgcn_mfma_f32_32x32x16_bf16(vf1, pf, acc[1], 0, 0, 0);
                __builtin_amdgcn_s_setprio(0);
            }
        }

        mw = mwn;
        __syncthreads();
    }

    // ---- in-block combine: half 1 -> LDS, half 0 merges + stores ----
    const int rloc = w * 32 + lq;
    float* Osh = (float*)SMEM;             // [128][68] f32
    float* Lsh = (float*)SMEM + 128 * 68;  // [128] f32

    if (half == 1) {
        #pragma unroll
        for (int dt = 0; dt < 2; ++dt)
            #pragma unroll
            for (int g = 0; g < 4; ++g) {
                f32x4 v = { acc[dt][g * 4 + 0], acc[dt][g * 4 + 1],
                            acc[dt][g * 4 + 2], acc[dt][g * 4 + 3] };
                *(f32x4*)(Osh + rloc * 68 + dt * 32 + 8 * g + 4 * h) = v;
            }
        if (h == 0) Lsh[rloc] = lacc[0];
    }
    __syncthreads();
    if (half == 0) {
        const float linv = 1.0f / (lacc[0] + Lsh[rloc]);
        unsigned short* Ar = att + ((size_t)b * SEQ + qrow) * DMODEL + hd * DHEAD;
        #pragma unroll
        for (int dt = 0; dt < 2; ++dt)
            #pragma unroll
            for (int g = 0; g < 4; ++g) {
                const int dh0 = dt * 32 + 8 * g + 4 * h;
                f32x4 p = *(const f32x4*)(Osh + rloc * 68 + dh0);
                ushort4 o;
                o.x = f2bf((acc[dt][g * 4 + 0] + p[0]) * linv);
                o.y = f2bf((acc[dt][g * 4 + 1] + p[1]) * linv);
                o.z = f2bf((acc[dt][g * 4 + 2] + p[2]) * linv);
                o.w = f2bf((acc[dt][g * 4 + 3] + p[3]) * linv);
                *(ushort4*)(Ar + dh0) = o;
            }
    }
}

// =====================================================================
// Output GEMM — R8 structure (64x128 dbuf, 48 KB LDS, 512 blocks);
// v12: non-temporal store on the final f32 C (consumed only by host).
// =====================================================================
__global__ __launch_bounds__(256) void out_gemm_kernel(
    const unsigned short* __restrict__ A, const unsigned short* __restrict__ Bt,
    float* __restrict__ C)
{
    const int bid = blockIdx.x;
    const int sx = bid >> 3;
    const int m0 = ((bid & 7) * 8 + (sx >> 3)) * 64;
    const int n0 = (sx & 7) * 128;

    const int t = threadIdx.x, lane = t & 63, w = t >> 6;
    const int lg = lane >> 4, ln = lane & 15;
    const int wx = w & 1, wy = w >> 1;

    __shared__ __align__(16) unsigned short SM[24576];

    f32x4 acc[2][4] = {};

    {
        unsigned short* Ad = SM;
        unsigned short* Bd = SM + 8192;
        #pragma unroll
        for (int i = 0; i < 4; ++i) {
            int s = (w * 4 + i) * 64 + lane;
            int n = s >> 3, c = (s & 7) ^ (n & 7);
            gld_lds16(Bt + (size_t)(n0 + n) * DMODEL + c * 8, Bd + (size_t)s * 8);
        }
        #pragma unroll
        for (int i = 0; i < 2; ++i) {
            int s = (w * 2 + i) * 64 + lane;
            int n = s >> 3, c = (s & 7) ^ (n & 7);
            gld_lds16(A + (size_t)(m0 + n) * DMODEL + c * 8, Ad + (size_t)s * 8);
        }
    }
    __syncthreads();

    for (int ki = 0; ki < 16; ++ki) {
        const int buf = ki & 1;

        if (ki < 15) {
            const int kk = (ki + 1) * 64;
            unsigned short* Ad = SM + (buf ^ 1) * 4096;
            unsigned short* Bd = SM + 8192 + (buf ^ 1) * 8192;
            #pragma unroll
            for (int i = 0; i < 4; ++i) {
                int s = (w * 4 + i) * 64 + lane;
                int n = s >> 3, c = (s & 7) ^ (n & 7);
                gld_lds16(Bt + (size_t)(n0 + n) * DMODEL + kk + c * 8, Bd + (size_t)s * 8);
            }
            #pragma unroll
            for (int i = 0; i < 2; ++i) {
                int s = (w * 2 + i) * 64 + lane;
                int n = s >> 3, c = (s & 7) ^ (n & 7);
                gld_lds16(A + (size_t)(m0 + n) * DMODEL + kk + c * 8, Ad + (size_t)s * 8);
            }
        }

        const unsigned short* Asb = SM + buf * 4096;
        const unsigned short* Bsb = SM + 8192 + buf * 8192;
        #pragma unroll
        for (int ks = 0; ks < 2; ++ks) {
            bf16x8 af[2], bf[4];
            #pragma unroll
            for (int rb = 0; rb < 2; ++rb) {
                int rr = wy * 32 + rb * 16 + ln;
                af[rb] = *(const bf16x8*)(Asb + rr * 64 + (((ks * 4 + lg) ^ (rr & 7)) * 8));
            }
            #pragma unroll
            for (int nb = 0; nb < 4; ++nb) {
                int n = wx * 64 + nb * 16 + ln;
                bf[nb] = *(const bf16x8*)(Bsb + n * 64 + (((ks * 4 + lg) ^ (n & 7)) * 8));
            }
            #pragma unroll
            for (int rb = 0; rb < 2; ++rb)
                #pragma unroll
                for (int nb = 0; nb < 4; ++nb)
                    acc[rb][nb] = __builtin_amdgcn_mfma_f32_16x16x32_bf16(
                        af[rb], bf[nb], acc[rb][nb], 0, 0, 0);
        }
        __syncthreads();
    }

    #pragma unroll
    for (int rb = 0; rb < 2; ++rb)
        #pragma unroll
        for (int nb = 0; nb < 4; ++nb)
            #pragma unroll
            for (int rr = 0; rr < 4; ++rr) {
                int grow = m0 + wy * 32 + rb * 16 + lg * 4 + rr;
                int gcol = n0 + wx * 64 + nb * 16 + ln;
                __builtin_nontemporal_store(acc[rb][nb][rr],
                                            C + (size_t)grow * DMODEL + gcol);
            }
}

extern "C" void kernel_launch(void* const* d_in, const int* in_sizes, int n_in,
                              void* d_out, int out_size, void* d_ws, size_t ws_size,
                              hipStream_t stream) {
    const float* q    = (const float*)d_in[0];
    const float* k    = (const float*)d_in[1];
    const float* v    = (const float*)d_in[2];
    const int*   mask = (const int*)  d_in[3];
    const float* Wq   = (const float*)d_in[4];
    const float* Wk   = (const float*)d_in[5];
    const float* Wv   = (const float*)d_in[6];
    const float* Wo   = (const float*)d_in[7];
    float* out = (float*)d_out;

    unsigned short* ws  = (unsigned short*)d_ws;
    const size_t n1 = (size_t)NB * NH * SEQ * DHEAD;      // 4,194,304 shorts
    const size_t nw = (size_t)NH * DHEAD * DMODEL;        // 1,048,576 shorts
    unsigned short* qh  = ws;
    unsigned short* kh  = qh + n1;
    unsigned short* vt  = kh + n1;                        // [bh][dh][seq]
    unsigned short* att = vt + n1;
    unsigned short* Wqt = att + n1;
    unsigned short* Wkt = Wqt + nw;
    unsigned short* Wvt = Wkt + nw;
    unsigned short* Wot = Wvt + nw;
    unsigned long long* mpack = (unsigned long long*)(Wot + nw);   // 1 MB
    unsigned short* qb = (unsigned short*)(mpack + (size_t)NB * SEQ * (SEQ / 64));
    unsigned short* kb = qb + n1;
    unsigned short* vb = kb + n1;

    prep_kernel<<<dim3(8192), 256, 0, stream>>>(
        mask, mpack, Wq, Wk, Wv, Wqt, Wkt, Wvt, Wo, Wot, q, k, v, qb, kb, vb);
    proj_gemm_kernel<<<dim3(768), 256, 0, stream>>>(qb, kb, vb, Wqt, Wkt, Wvt, qh, kh, vt);
    attn_kernel<<<dim3(512), 512, 0, stream>>>(qh, kh, vt, mpack, att);
    out_gemm_kernel<<<dim3(512), 256, 0, stream>>>(att, Wot, out);
}